// Round 5
// baseline (39627.063 us; speedup 1.0000x reference)
//
#include <hip/hip_runtime.h>
#include <stdint.h>

// Persistent-kernel autoregressive decode for Generator_18124761989654.
// R4 -> R5: flat LLC-coherent scheme (R3 base), restructured:
//  - 128 WGs x 1024 threads (16 waves/CU), launch_bounds(1024,1).
//  - 3 global barriers/step (was 6): P1 (16 WGs: cross+QKV0+attn0+partial O),
//    P2 (16 WGs: z2-LN + K2V2 + Q2n), P3 (128 WGs: attn1 row n redundant +
//    z3-LN + logits + argmax). Single-writer ws buffers; monotonic counters.
//  - soft_W no longer LDS-pinned: loop barriers are fence-free so per-XCD L2
//    stays warm all 63 steps (2MB slices/XCD). LDS freed for 100KB work tiles.
//  - sc1 load loops hand-batched (load-8-then-use) to overlap LLC round trips.

#define NWG 128
#define NT 1024
#define AS __ATOMIC_RELAXED
#define AG __HIP_MEMORY_SCOPE_AGENT

typedef unsigned long long u64;

__device__ __forceinline__ float ld1(const float* p){
  return __hip_atomic_load(p, AS, AG);
}
__device__ __forceinline__ void st1(float* p, float v){
  __hip_atomic_store(p, v, AS, AG);
}

__device__ __forceinline__ float wredsum(float v){
#pragma unroll
  for (int m=32;m;m>>=1) v += __shfl_xor(v,m,64);
  return v;
}
__device__ __forceinline__ u64 shflx64(u64 v,int m){
  unsigned int lo=(unsigned int)(v&0xffffffffull), hi=(unsigned int)(v>>32);
  lo=__shfl_xor(lo,m,64); hi=__shfl_xor(hi,m,64);
  return (((u64)hi)<<32)|(u64)lo;
}
__device__ __forceinline__ float pe_val(int l, int e){
  int j = e >> 1;
  float dv = expf((float)(2*j) * (-0.035977892078031970f));
  float arg = (float)l * dv;
  return (e & 1) ? cosf(arg) : sinf(arg);
}

// fenced device barrier (prelude only; epoch-equality => poison-safe)
__device__ __forceinline__ void gbar_f(int* arr, int* rel, int ep){
  __syncthreads();
  if (threadIdx.x==0){
    __builtin_amdgcn_fence(__ATOMIC_RELEASE, "agent");
    __hip_atomic_store(arr + blockIdx.x*16, ep, AS, AG);
  }
  if (blockIdx.x==0){
    if (threadIdx.x < NWG){
      while (__hip_atomic_load(arr + threadIdx.x*16, AS, AG) != ep)
        __builtin_amdgcn_s_sleep(1);
    }
    __syncthreads();
    if (threadIdx.x==0)
      __hip_atomic_store(rel, ep, AS, AG);
  }
  if (threadIdx.x==0){
    while (__hip_atomic_load(rel, AS, AG) != ep)
      __builtin_amdgcn_s_sleep(1);
    __builtin_amdgcn_fence(__ATOMIC_ACQUIRE, "agent");
  }
  __syncthreads();
}

extern "C" __global__ __launch_bounds__(1024, 1)
void gen18124_kernel(const float* __restrict__ noise,
                     const float* __restrict__ iw, const float* __restrict__ ib,
                     const float* __restrict__ Wq, const float* __restrict__ bq,
                     const float* __restrict__ Wk, const float* __restrict__ bk,
                     const float* __restrict__ Wv, const float* __restrict__ bv,
                     const float* __restrict__ Wo, const float* __restrict__ bo,
                     const float* __restrict__ lng, const float* __restrict__ lnb,
                     const float* __restrict__ emb, const float* __restrict__ sw,
                     const float* __restrict__ sb,
                     int* __restrict__ out, float* __restrict__ ws)
{
  const float ISQ = 0.17677669529663687f; // 1/sqrt(32)
  __shared__ float sm[25600];
  __shared__ float redv[8];
  __shared__ u64 redU[2];
  __shared__ int s_win;

  // ---- workspace layout (float offsets) ----
  float* WVEC = ws;            // 64
  float* SKC  = ws+64;         // [2][256]
  float* SVC  = ws+576;        // [2][256]
  float* KAP  = ws+1088;       // [2][8][256]
  float* UT   = ws+5184;       // [2][8][256]
  float* CC   = ws+9280;       // [2][256]
  float* BETA = ws+9792;       // [2][8]
  int* ARR = (int*)(ws+9824);  // gbar_f flags 128*16
  int* REL = (int*)(ws+11872);
  float* Yg   = ws+11876;      // [64][256]
  float* R1b  = ws+28260;      // [64][256]
  float* Z2P  = ws+44644;      // [8][64][256]
  float* KB2  = ws+175716;     // [64][256]
  float* VB2  = ws+192100;     // [64][256]
  float* Q2N  = ws+208484;     // [256]
  float* R2N  = ws+208740;     // [256]
  u64*  SLOT64 = (u64*)(ws+209000);  // [64], 8B-aligned
  int*  F1   = (int*)(ws+209200);
  int*  F2   = (int*)(ws+209232);
  int*  LCNT = (int*)(ws+209264);

  const int wg = blockIdx.x, t = threadIdx.x;
  const int lane = t&63, wave = t>>6;
  int ep = 0;

  // ================= Prelude phase 0 =================
  {
    if (wg==2){
      if (t<64) __hip_atomic_store(&SLOT64[t], 0ull, AS, AG);
      if (t==64) __hip_atomic_store(F1, 0, AS, AG);
      if (t==65) __hip_atomic_store(F2, 0, AS, AG);
      if (t==66) __hip_atomic_store(LCNT, 0, AS, AG);
    }
    // column sums of Wk/Wv (2 cols per WG, 2 layers)
    int c0 = 2*wg;
    int r = t&255, grp = t>>8;      // grp: 0=WkL0 1=WkL1 2=WvL0 3=WvL1
    const float* M = (grp>=2)? Wv : Wk;
    int base = (grp&1)*65536;
    float a0 = M[base + r*256 + c0];
    float a1 = M[base + r*256 + c0 + 1];
    a0=wredsum(a0); a1=wredsum(a1);
    if (lane==0){ sm[wave*2]=a0; sm[wave*2+1]=a1; }
    __syncthreads();
    if (t<8){
      int G=t>>1, j=t&1;
      float s=0.f;
      for (int i=0;i<4;i++) s += sm[(G*4+i)*2+j];
      if (G<2) SKC[(G&1)*256+c0+j]=s;
      else     SVC[(G&1)*256+c0+j]=s;
    }
    __syncthreads();
    if (wg==0){
      float* wl = sm+64;
      if (t<64) wl[t] = noise[t];
      __syncthreads();
      for (int i=0;i<4;i++){
        float acc=0.f;
        if (t<64){
          for (int in_=0;in_<64;in_++) acc += wl[in_]*iw[(i*64+in_)*64+t];
          acc += ib[i*64+t];
        }
        __syncthreads();
        if (t<64) wl[t]=acc;
        __syncthreads();
      }
      if (t<64) WVEC[t]=wl[t];
    }
    if (wg==1){
      if (t<256) Yg[t] = emb[t] + pe_val(0,t);  // normal store; fenced barrier publishes
      if (t==0) out[0]=0;
    }
  }
  gbar_f(ARR,REL,++ep);

  // ================= Prelude phase 1: tables =================
  {
    int c0 = 2*wg;
    int r = t&255, grp = t>>8;    // i=grp>>1, cl=grp&1
    int i0=grp>>1, cl0=grp&1;
    float p = bv[i0*256+r]*Wo[i0*65536 + r*256 + c0+cl0];
    p=wredsum(p);
    if (lane==0) sm[wave]=p;
    __syncthreads();
    if (t<4){
      float s=sm[t*4]+sm[t*4+1]+sm[t*4+2]+sm[t*4+3];
      int i=t>>1, cl=t&1;
      CC[i*256+c0+cl] = s + bo[i*256+c0+cl];
    }
    if (t<32){
      int i=t>>4, h=(t>>1)&7, c=c0+(t&1);
      float s=0.f;
      for (int e2=0;e2<32;e2++) s += SVC[i*256+h*32+e2]*Wo[i*65536+(h*32+e2)*256+c];
      UT[(i*8+h)*256+c]=s;
    } else if (t<64){
      int u=t-32, i=u>>4, h=(u>>1)&7, e=c0+(u&1);
      float s=0.f;
      for (int c2=0;c2<32;c2++) s += Wq[i*65536+e*256+h*32+c2]*SKC[i*256+h*32+c2];
      KAP[(i*8+h)*256+e]=s;
    }
    if (wg==0 && t>=64 && t<80){
      int u=t-64, i=u>>3, h=u&7;
      float s=0.f;
      for (int c2=0;c2<32;c2++) s += bq[i*256+h*32+c2]*SKC[i*256+h*32+c2];
      BETA[i*8+h]=s;
    }
    if (t==0) s_win=0;
  }
  gbar_f(ARR,REL,++ep);

  const int h = wg&7, half = (wg>>3)&1, q0 = half*32;

  // LDS region aliases
  float* XL  = sm;          // [64][256]  P1: Y -> R1 in place
  float* KL  = sm+16384;    // [64][33]
  float* VL  = sm+18496;    // [64][33]
  float* QL  = sm+20608;    // [32][33]
  float* SCb = sm+21664;    // [32][65]
  float* AOL = sm+23744;    // [32][33]
  float* M8  = sm+24800;    // [64][8]
  float* R2L = sm;          // P2: [32][256]
  float* QnL = sm;          // P3 aliases
  float* R2nL= sm+256;
  float* SC2 = sm+512;      // [8][65]
  float* AOL2= sm+1032;     // [256]
  float* outn= sm+1288;     // [256]
  float* pp  = sm+1544;     // [8][128]

  // ================= decode loop =================
  for (int tok=1; tok<64; tok++){
    const int n = tok-1;

    if (wg < 16){
      // ======== P1: Y load, cross blocks -> R1, QKV0, attn0, partial O ========
      {
        int v = s_win;
        for (int i=t;i<16384;i+=NT){
          int q=i>>8, e=i&255;
          float val;
          if (q>n) val=0.f;
          else if (q==n && tok>1){
            val = emb[v*256+e] + pe_val(n,e);
            if (wg==0) st1(&Yg[i], val);
          } else {
            val = ld1(&Yg[i]);
          }
          XL[i]=val;
        }
      }
      __syncthreads();
      // cross blocks
      for (int blk=0; blk<2; blk++){
        {
          int q=t>>4, h2=(t>>1)&7, p2=t&1;
          const float* kap = KAP + (blk*8+h2)*256;
          float part=0.f;
          int e0=p2*128;
          for (int e=e0;e<e0+128;e++) part += XL[q*256+e]*kap[e];
          part += __shfl_xor(part,1,64);
          if (p2==0){
            float alpha = (part + BETA[blk*8+h2]) * ISQ;
            float mx=-3.4e38f;
            for (int k=0;k<tok;k++) mx = fmaxf(mx, alpha*WVEC[k]);
            float sn=0.f, sd=0.f;
            for (int k=0;k<tok;k++){
              float e_=expf(alpha*WVEC[k]-mx);
              sn+=e_*WVEC[k]; sd+=e_;
            }
            M8[q*8+h2]=sn/sd;
          }
        }
        __syncthreads();
        {
          int q=t>>4, s=t&15;
          float zv[16]; float zs=0.f,zq=0.f;
          const float* cc = CC + blk*256;
          for (int i=0;i<16;i++){
            int e=s*16+i;
            float z = cc[e] + XL[q*256+e];
#pragma unroll
            for (int h2=0;h2<8;h2++) z += M8[q*8+h2]*UT[(blk*8+h2)*256+e];
            zv[i]=z; zs+=z; zq+=z*z;
          }
#pragma unroll
          for (int m=8;m;m>>=1){ zs+=__shfl_xor(zs,m,64); zq+=__shfl_xor(zq,m,64); }
          float mu=zs*(1.f/256.f), var=zq*(1.f/256.f)-mu*mu;
          float rstd=1.f/sqrtf(var+1e-5f);
          for (int i=0;i<16;i++){
            int e=s*16+i;
            XL[q*256+e]=(zv[i]-mu)*rstd*lng[blk*256+e]+lnb[blk*256+e];
          }
        }
        __syncthreads();
      }
      // K0,V0 (all rows, head h) + Q0 (my half)
      {
        for (int i2=0;i2<4;i2++){
          int outid=i2*1024+t;
          int q=outid>>6, m=(outid>>5)&1, c=outid&31;
          int col=h*32+c;
          const float* W = m? Wv : Wk;
          float acc = m? bv[col] : bk[col];
          for (int e=0;e<256;e++) acc += XL[q*256+e]*W[e*256+col];
          if (m) VL[q*33+c]=acc; else KL[q*33+c]=acc;
        }
        int qm=t>>5, c=t&31, col=h*32+c;
        int q=q0+qm;
        float acc=bq[col];
        for (int e=0;e<256;e++) acc += XL[q*256+e]*Wq[e*256+col];
        QL[qm*33+c]=acc;
      }
      __syncthreads();
      // scores
      for (int i2=0;i2<2;i2++){
        int id=i2*1024+t; int qm=id>>6, k=id&63;
        float sc=-3.4e38f;
        if (k<tok){
          sc=0.f;
#pragma unroll
          for (int j=0;j<32;j++) sc += QL[qm*33+j]*KL[k*33+j];
          sc*=ISQ;
        }
        SCb[qm*65+k]=sc;
      }
      __syncthreads();
      // softmax
      {
        int qm=t>>5, l=t&31;
        float s1=SCb[qm*65+l], s2=SCb[qm*65+l+32];
        float mx=fmaxf(s1,s2);
#pragma unroll
        for (int m=16;m;m>>=1) mx=fmaxf(mx,__shfl_xor(mx,m,64));
        float e1=(l<tok)? expf(s1-mx):0.f;
        float e2=(l+32<tok)? expf(s2-mx):0.f;
        float sd=e1+e2;
#pragma unroll
        for (int m=16;m;m>>=1) sd+=__shfl_xor(sd,m,64);
        float inv=1.f/sd;
        SCb[qm*65+l]=e1*inv; SCb[qm*65+l+32]=e2*inv;
      }
      __syncthreads();
      // AV
      {
        int qm=t>>5, j=t&31;
        float oa=0.f;
        for (int k=0;k<tok;k++) oa += SCb[qm*65+k]*VL[k*33+j];
        AOL[qm*33+j]=oa;
      }
      __syncthreads();
      // partial O-proj -> Z2P; wg0 stores R1
      for (int i2=0;i2<8;i2++){
        int id=i2*1024+t; int qm=id>>8, col=id&255;
        int qg=q0+qm;
        if (qg<tok){
          float acc=0.f;
#pragma unroll
          for (int j=0;j<32;j++) acc += AOL[qm*33+j]*Wo[(h*32+j)*256+col];
          st1(&Z2P[(h*64+qg)*256+col], acc);
        }
      }
      if (wg==0){
        for (int i=t;i<16384;i+=NT){
          int q=i>>8;
          if (q<tok) st1(&R1b[i], XL[i]);
        }
      }
      // ---- bar1 (16 WGs) ----
      __syncthreads();
      if (t==0){
        __hip_atomic_fetch_add(F1,1,AS,AG);
        while (__hip_atomic_load(F1,AS,AG) < 16*tok) __builtin_amdgcn_s_sleep(4);
      }
      __syncthreads();

      // ======== P2: z2 assemble + LN -> R2L, K2V2, Q2n, R2N ========
      {
        int qm=t>>5, s=t&31; int q=q0+qm;
        float zv[8]; float zs=0.f,zq=0.f;
        if (q<tok){
          int e0=s*8;
          float r1[8];
#pragma unroll
          for (int i=0;i<8;i++) r1[i]=ld1(&R1b[q*256+e0+i]);
#pragma unroll
          for (int i=0;i<8;i++) zv[i]=bo[e0+i]+r1[i];
          for (int h2=0;h2<8;h2++){
            float w8[8];
#pragma unroll
            for (int i=0;i<8;i++) w8[i]=ld1(&Z2P[(h2*64+q)*256+e0+i]);
#pragma unroll
            for (int i=0;i<8;i++) zv[i]+=w8[i];
          }
#pragma unroll
          for (int i=0;i<8;i++){ zs+=zv[i]; zq+=zv[i]*zv[i]; }
        }
#pragma unroll
        for (int m=16;m;m>>=1){ zs+=__shfl_xor(zs,m,64); zq+=__shfl_xor(zq,m,64); }
        if (q<tok){
          float mu=zs*(1.f/256.f), var=zq*(1.f/256.f)-mu*mu;
          float rstd=1.f/sqrtf(var+1e-5f);
          int e0=s*8;
#pragma unroll
          for (int i=0;i<8;i++)
            R2L[qm*256+e0+i]=(zv[i]-mu)*rstd*lng[e0+i]+lnb[e0+i];
        }
      }
      __syncthreads();
      // K2,V2 (my half rows, head h)
      for (int i2=0;i2<2;i2++){
        int id=i2*1024+t; int qm=id>>6, m=(id>>5)&1, c=id&31;
        int q=q0+qm; int col=h*32+c;
        if (q<tok){
          const float* W = m? (Wv+65536):(Wk+65536);
          float acc = m? bv[256+col]:bk[256+col];
          for (int e=0;e<256;e++) acc += R2L[qm*256+e]*W[e*256+col];
          if (m) st1(&VB2[q*256+col], acc); else st1(&KB2[q*256+col], acc);
        }
      }
      if ((n>>5)==half){
        if (t<32){
          int col=h*32+t;
          float acc=bq[256+col];
          int qm=n&31;
          for (int e=0;e<256;e++) acc += R2L[qm*256+e]*Wq[65536+e*256+col];
          st1(&Q2N[col], acc);
        }
        if (h==0 && t>=64 && t<320){
          int e=t-64;
          st1(&R2N[e], R2L[(n&31)*256+e]);
        }
      }
      __syncthreads();
      if (t==0) __hip_atomic_fetch_add(F2,1,AS,AG);
    } // wg<16

    // ---- bar2 (all 128 wait for 16 producers) ----
    if (t==0){
      while (__hip_atomic_load(F2,AS,AG) < 16*tok) __builtin_amdgcn_s_sleep(4);
    }
    __syncthreads();

    // ======== P3: attn1 row n (redundant) + z3 LN + logits + argmax ========
    if (t<256){ QnL[t]=ld1(&Q2N[t]); R2nL[t]=ld1(&R2N[t]); }
    __syncthreads();
    if (t<512){
      int h2=t>>6, k=t&63;
      float sc=-3.4e38f;
      if (k<tok){
        sc=0.f;
        for (int j0=0;j0<32;j0+=8){
          float kv[8];
#pragma unroll
          for (int i=0;i<8;i++) kv[i]=ld1(&KB2[k*256+h2*32+j0+i]);
#pragma unroll
          for (int i=0;i<8;i++) sc += QnL[h2*32+j0+i]*kv[i];
        }
        sc*=ISQ;
      }
      SC2[h2*65+k]=sc;
    }
    __syncthreads();
    if (t<256){
      int h2=t>>5, l=t&31;
      float s1=SC2[h2*65+l], s2=SC2[h2*65+l+32];
      float mx=fmaxf(s1,s2);
#pragma unroll
      for (int m=16;m;m>>=1) mx=fmaxf(mx,__shfl_xor(mx,m,64));
      float e1=(l<tok)? expf(s1-mx):0.f;
      float e2=(l+32<tok)? expf(s2-mx):0.f;
      float sd=e1+e2;
#pragma unroll
      for (int m=16;m;m>>=1) sd+=__shfl_xor(sd,m,64);
      float inv=1.f/sd;
      SC2[h2*65+l]=e1*inv; SC2[h2*65+l+32]=e2*inv;
    }
    __syncthreads();
    if (t<256){
      int h2=t>>5;
      float oa=0.f;
      int k=0;
      while (k<tok){
        int kn = (tok-k<8)?(tok-k):8;
        float vv[8];
        for (int i=0;i<kn;i++) vv[i]=ld1(&VB2[(k+i)*256+t]);
        for (int i=0;i<kn;i++) oa += SC2[h2*65+k+i]*vv[i];
        k+=kn;
      }
      AOL2[t]=oa;
    }
    __syncthreads();
    if (t<256){
      float z = bo[256+t] + R2nL[t];
      for (int j=0;j<256;j++) z += AOL2[j]*Wo[65536+j*256+t];
      outn[t]=z;
      float zs=wredsum(z), zq=wredsum(z*z);
      if (lane==0){ redv[wave]=zs; redv[4+wave]=zq; }
    }
    __syncthreads();
    if (t<256){
      float ts=redv[0]+redv[1]+redv[2]+redv[3];
      float tq=redv[4]+redv[5]+redv[6]+redv[7];
      float mu=ts*(1.f/256.f), var=tq*(1.f/256.f)-mu*mu;
      float rstd=1.f/sqrtf(var+1e-5f);
      outn[t]=(outn[t]-mu)*rstd*lng[256+t]+lnb[256+t];
    }
    __syncthreads();
    // logits: 125 cols per WG, e split 8 ways
    {
      int c=t&127, eb=t>>7;
      float acc=0.f;
      if (c<125){
        int base=wg*125+c;
        for (int e=eb*32;e<eb*32+32;e++) acc += outn[e]*sw[e*16000+base];
      }
      pp[eb*128+c]=acc;
    }
    __syncthreads();
    {
      u64 key=0ull;
      if (t<128){
        if (t<125){
          float lg=sb[wg*125+t];
#pragma unroll
          for (int eb=0;eb<8;eb++) lg+=pp[eb*128+t];
          int v=wg*125+t;
          unsigned int fb=__float_as_uint(lg);
          fb=(fb&0x80000000u)? ~fb : (fb|0x80000000u);
          key=(((u64)fb)<<32)|(u64)(~(unsigned int)v);
        }
#pragma unroll
        for (int m=32;m;m>>=1){ u64 o=shflx64(key,m); key=(o>key)?o:key; }
        if (lane==0) redU[wave]=key;
      }
    }
    __syncthreads();
    if (t==0){
      u64 kk=redU[0]; if (redU[1]>kk) kk=redU[1];
      __hip_atomic_fetch_max(&SLOT64[tok], kk, AS, AG);
    }
    __syncthreads();   // drains t0's atomicMax before the counter add
    if (t==0){
      __hip_atomic_fetch_add(LCNT,1,AS,AG);
      while (__hip_atomic_load(LCNT,AS,AG) < 128*tok) __builtin_amdgcn_s_sleep(4);
      u64 sf=__hip_atomic_load(&SLOT64[tok],AS,AG);
      s_win=(int)(~(unsigned int)(sf&0xffffffffull));
      if (wg==0) out[tok]=s_win;
    }
    __syncthreads();
  }
}

extern "C" void kernel_launch(void* const* d_in, const int* in_sizes, int n_in,
                              void* d_out, int out_size, void* d_ws, size_t ws_size,
                              hipStream_t stream)
{
  (void)in_sizes; (void)n_in; (void)out_size; (void)ws_size;
  hipLaunchKernelGGL(gen18124_kernel, dim3(NWG), dim3(NT), 0, stream,
    (const float*)d_in[0],  (const float*)d_in[1],  (const float*)d_in[2],
    (const float*)d_in[3],  (const float*)d_in[4],  (const float*)d_in[5],
    (const float*)d_in[6],  (const float*)d_in[7],  (const float*)d_in[8],
    (const float*)d_in[9],  (const float*)d_in[10], (const float*)d_in[11],
    (const float*)d_in[12], (const float*)d_in[13], (const float*)d_in[14],
    (const float*)d_in[15], (int*)d_out, (float*)d_ws);
}

// Round 6
// 29424.469 us; speedup vs baseline: 1.3467x; 1.3467x over previous
//
#include <hip/hip_runtime.h>
#include <stdint.h>

// Persistent-kernel autoregressive decode for Generator_18124761989654.
// R5 -> R6: minimize sc1 (LLC-coherent) op count AND barrier count.
//  - 32 WGs x 512 threads. Active identity (h=wg&7, half=wg>>3) for wg<16.
//  - C1: Y cached in LDS per half; R1 recomputed locally (redundant VALU,
//    zero communication); K0/V0 head-slices -> global (32K dwords).
//  - C2: attn0 per (h,half); exchanges only 32-dim attn outputs OV (16K).
//  - C3: per-(half,h) 4 rows: O-proj+residual+LN row-local, K2/V2 all heads
//    -> global (32K); row-n owner writes R2N/q2.
//  - E2: 8 head-WGs: attn1 row n; writes o3 (256 dwords total).
//  - H: all 32 WGs: row-n O-proj redundant in-register, LN, 500 logit cols
//    each with PLAIN L2-warm sw loads, packed-argmax, WIN[tok] handoff.
//  - 5 x 32-arrival counter barriers/step + F4 argmax counter. All counters
//    monotonic, zeroed in prelude (poison-safe).

#define NWG 32
#define NT 512
#define AS __ATOMIC_RELAXED
#define AG __HIP_MEMORY_SCOPE_AGENT

typedef unsigned long long u64;

__device__ __forceinline__ float ld1(const float* p){
  return __hip_atomic_load(p, AS, AG);
}
__device__ __forceinline__ void st1(float* p, float v){
  __hip_atomic_store(p, v, AS, AG);
}

__device__ __forceinline__ float wredsum(float v){
#pragma unroll
  for (int m=32;m;m>>=1) v += __shfl_xor(v,m,64);
  return v;
}
__device__ __forceinline__ float wredmax(float v){
#pragma unroll
  for (int m=32;m;m>>=1) v = fmaxf(v,__shfl_xor(v,m,64));
  return v;
}
__device__ __forceinline__ u64 shflx64(u64 v,int m){
  unsigned int lo=(unsigned int)(v&0xffffffffull), hi=(unsigned int)(v>>32);
  lo=__shfl_xor(lo,m,64); hi=__shfl_xor(hi,m,64);
  return (((u64)hi)<<32)|(u64)lo;
}
__device__ __forceinline__ float pe_val(int l, int e){
  int j = e >> 1;
  float dv = expf((float)(2*j) * (-0.035977892078031970f));
  float arg = (float)l * dv;
  return (e & 1) ? cosf(arg) : sinf(arg);
}

// fenced device barrier (prelude only; epoch-equality => poison-safe)
__device__ __forceinline__ void gbar_f(int* arr, int* rel, int ep){
  __syncthreads();
  if (threadIdx.x==0){
    __builtin_amdgcn_fence(__ATOMIC_RELEASE, "agent");
    __hip_atomic_store(arr + blockIdx.x*16, ep, AS, AG);
  }
  if (blockIdx.x==0){
    if (threadIdx.x < NWG){
      while (__hip_atomic_load(arr + threadIdx.x*16, AS, AG) != ep)
        __builtin_amdgcn_s_sleep(1);
    }
    __syncthreads();
    if (threadIdx.x==0)
      __hip_atomic_store(rel, ep, AS, AG);
  }
  if (threadIdx.x==0){
    while (__hip_atomic_load(rel, AS, AG) != ep)
      __builtin_amdgcn_s_sleep(1);
    __builtin_amdgcn_fence(__ATOMIC_ACQUIRE, "agent");
  }
  __syncthreads();
}

// fence-free monotonic counter barrier (decode loop)
__device__ __forceinline__ void cbar(int* f, int tgt){
  __syncthreads();
  if (threadIdx.x==0){
    __hip_atomic_fetch_add(f,1,AS,AG);
    while (__hip_atomic_load(f,AS,AG) < tgt) __builtin_amdgcn_s_sleep(2);
  }
  __syncthreads();
}

extern "C" __global__ __launch_bounds__(512, 1)
void gen18124_kernel(const float* __restrict__ noise,
                     const float* __restrict__ iw, const float* __restrict__ ib,
                     const float* __restrict__ Wq, const float* __restrict__ bq,
                     const float* __restrict__ Wk, const float* __restrict__ bk,
                     const float* __restrict__ Wv, const float* __restrict__ bv,
                     const float* __restrict__ Wo, const float* __restrict__ bo,
                     const float* __restrict__ lng, const float* __restrict__ lnb,
                     const float* __restrict__ emb, const float* __restrict__ sw,
                     const float* __restrict__ sb,
                     int* __restrict__ out, float* __restrict__ ws)
{
  const float ISQ = 0.17677669529663687f; // 1/sqrt(32)
  __shared__ int s_win;
  __shared__ float sredv[16];
  __shared__ float redc[16];
  __shared__ u64 sredU[8];
  extern __shared__ float pool[];

  // ---- LDS pool layout (floats) ----
  float* YH  = pool;          // [32][258] own-half Y cache (persistent)
  float* R1H = pool+8256;     // [32][258] own-half R1 (per step)
  float* K0L = pool+16512;    // [32][33]
  float* V0L = pool+17568;    // [32][33]
  float* Q0L = pool+18624;    // [32][33]
  float* S   = pool+19680;    // 7424-float phase scratch (aliased)

  // ---- workspace (float offsets) ----
  float* WVEC = ws;            // 64
  float* SKC  = ws+64;         // [2][256]
  float* SVC  = ws+576;        // [2][256]
  float* KAP  = ws+1088;       // [2][8][256]
  float* UT   = ws+5184;       // [2][8][256]
  float* CC   = ws+9280;       // [2][256]
  float* BETA = ws+9792;       // [2][8]
  int* ARR = (int*)(ws+9824);  // 32*16 gbar_f flags
  int* REL = (int*)(ws+10336);
  int* F   = (int*)(ws+10340); // F[0..3] barriers, F[4] argmax
  int* WIN = (int*)(ws+10348); // [64] winner+1 per step
  u64* SLOT64 = (u64*)(ws+10416); // [64]
  float* KB  = ws+10544;       // [64][256]
  float* VB  = ws+26928;       // [64][256]
  float* OV  = ws+43312;       // [64][256] attn0 outputs (head-concat)
  float* K2G = ws+59696;       // [64][256]
  float* V2G = ws+76080;       // [64][256]
  float* Q2G = ws+92464;       // [256]
  float* R2N = ws+92720;       // [256]
  float* O3G = ws+92976;       // [256]

  const int wg = blockIdx.x, t = threadIdx.x;
  int ep = 0;

  // ================= Prelude 0: zero ctrl, colsums, WVEC =================
  {
    if (wg==1){
      if (t<64) __hip_atomic_store(&SLOT64[t], 0ull, AS, AG);
      if (t>=64 && t<69) __hip_atomic_store(&F[t-64], 0, AS, AG);
      if (t>=128 && t<192) __hip_atomic_store(&WIN[t-128], (t==128)?1:0, AS, AG);
      if (t==200) out[0]=0;
    }
    // colsums of Wk/Wv both layers: col = wg*8 + wave
    for (int it=0; it<4; it++){
      const float* M = (it>=2)? Wv : Wk;
      int base=(it&1)*65536;
      int col=wg*8+(t>>6);
      int r0=(t&63)*4;
      float a=0.f;
#pragma unroll
      for (int i=0;i<4;i++) a+=M[base+(r0+i)*256+col];
      a=wredsum(a);
      if ((t&63)==0){
        if (it<2) SKC[(it&1)*256+col]=a; else SVC[(it&1)*256+col]=a;
      }
    }
    if (wg==0){
      float* wl=S;
      if (t<64) wl[t]=noise[t];
      __syncthreads();
      for (int i=0;i<4;i++){
        float acc=0.f;
        if (t<64){
          for (int in_=0;in_<64;in_++) acc += wl[in_]*iw[(i*64+in_)*64+t];
          acc += ib[i*64+t];
        }
        __syncthreads();
        if (t<64) wl[t]=acc;
        __syncthreads();
      }
      if (t<64) WVEC[t]=wl[t];
    }
  }
  gbar_f(ARR,REL,++ep);

  // ================= Prelude 1: tables =================
  {
    int c0=wg*8;
    { // CC: 16 ents x 32-thread partial
      int ent=t>>5, rr=t&31;
      int i=ent>>3, c=c0+(ent&7);
      float p=0.f;
      for (int r=rr*8;r<rr*8+8;r++) p += bv[i*256+r]*Wo[i*65536+r*256+c];
#pragma unroll
      for (int m=16;m;m>>=1) p+=__shfl_xor(p,m,64);
      if ((t&31)==0) CC[i*256+c]=p+bo[i*256+c];
    }
    if (t<128){ // UT
      int i=t>>6, h=(t>>3)&7, c=c0+(t&7);
      float s=0.f;
      for (int e2=0;e2<32;e2++) s += SVC[i*256+h*32+e2]*Wo[i*65536+(h*32+e2)*256+c];
      UT[(i*8+h)*256+c]=s;
    } else if (t<256){ // KAP
      int ent=wg*128+(t-128);
      int i=ent>>11, h=(ent>>8)&7, e=ent&255;
      float s=0.f;
      for (int c2=0;c2<32;c2++) s += Wq[i*65536+e*256+h*32+c2]*SKC[i*256+h*32+c2];
      KAP[(i*8+h)*256+e]=s;
    } else if (wg==0 && t<272){ // BETA
      int u=t-256, i=u>>3, h=u&7;
      float s=0.f;
      for (int c2=0;c2<32;c2++) s += bq[i*256+h*32+c2]*SKC[i*256+h*32+c2];
      BETA[i*8+h]=s;
    }
  }
  gbar_f(ARR,REL,++ep);

  const int h = wg&7, half = (wg>>3)&1;
  const int rlo = half*32;

  // ================= decode loop =================
  for (int tok=1; tok<64; tok++){
    const int n = tok-1;
    int nrows = tok-rlo; nrows = nrows<0?0:(nrows>32?32:nrows);

    // ======== C1: Y append + R1 (local) + K0/V0/Q0 head h ========
    if (wg<16){
      if (n>=rlo && n<rlo+32){
        if (t==0){
          int w;
          do { w=__hip_atomic_load(&WIN[n],AS,AG); } while(w==0);
          s_win=w-1;
        }
        __syncthreads();
        int v=s_win;
        for (int c=t;c<256;c+=NT) YH[(n-rlo)*258+c]=emb[v*256+c]+pe_val(n,c);
      }
      __syncthreads();
      if (nrows>0){
        float* m8L=S; // [32][8]
        for (int i=t;i<nrows*256;i+=NT){ int qm=i>>8,c=i&255; R1H[qm*258+c]=YH[qm*258+c]; }
        __syncthreads();
        for (int blk=0;blk<2;blk++){
          if (t<nrows*8){
            int qm=t>>3, h2=t&7;
            const float* kap=&KAP[(blk*8+h2)*256];
            float dot=0.f;
            for (int e=0;e<256;e++) dot += R1H[qm*258+e]*kap[e];
            float alpha=(dot+BETA[blk*8+h2])*ISQ;
            float mx=-3.4e38f;
            for (int k=0;k<tok;k++) mx=fmaxf(mx,alpha*WVEC[k]);
            float sn=0.f,sd=0.f;
            for (int k=0;k<tok;k++){ float e_=expf(alpha*WVEC[k]-mx); sn+=e_*WVEC[k]; sd+=e_; }
            m8L[qm*8+h2]=sn/sd;
          }
          __syncthreads();
          {
            int qm=t>>4, s=t&15;
            if (qm<nrows){
              float zv[16]; float zs=0.f,zq=0.f;
              for (int i=0;i<16;i++){
                int e=s*16+i;
                float z=CC[blk*256+e]+R1H[qm*258+e];
#pragma unroll
                for (int h2=0;h2<8;h2++) z+=m8L[qm*8+h2]*UT[(blk*8+h2)*256+e];
                zv[i]=z; zs+=z; zq+=z*z;
              }
#pragma unroll
              for (int m=8;m;m>>=1){ zs+=__shfl_xor(zs,m,64); zq+=__shfl_xor(zq,m,64); }
              float mu=zs*(1.f/256.f), var=zq*(1.f/256.f)-mu*mu;
              float rstd=1.f/sqrtf(var+1e-5f);
              for (int i=0;i<16;i++){
                int e=s*16+i;
                R1H[qm*258+e]=(zv[i]-mu)*rstd*lng[blk*256+e]+lnb[blk*256+e];
              }
            }
          }
          __syncthreads();
        }
        // K0/V0/Q0 (head h, own-half rows)
        for (int i2=0;i2<6;i2++){
          int ent=i2*NT+t;
          int m=ent>>10, qm=(ent>>5)&31, c=ent&31;
          if (qm<nrows){
            int col=h*32+c;
            const float* W=(m==0)?Wk:((m==1)?Wv:Wq);
            float acc=(m==0)?bk[col]:((m==1)?bv[col]:bq[col]);
            for (int e=0;e<256;e++) acc += R1H[qm*258+e]*W[e*256+col];
            if (m==0){ K0L[qm*33+c]=acc; st1(&KB[(rlo+qm)*256+col],acc); }
            else if (m==1){ V0L[qm*33+c]=acc; st1(&VB[(rlo+qm)*256+col],acc); }
            else Q0L[qm*33+c]=acc;
          }
        }
      }
    }
    cbar(&F[0], 32*tok);

    // ======== C2: attn0 (head h, own-half rows) -> OV ========
    if (wg<16 && nrows>0){
      float* KF=S; float* VF=S+2112; float* SC=S+4224; float* OL=S+6304;
      const int orlo=(1-half)*32;
      int onr=tok-orlo; onr=onr<0?0:(onr>32?32:onr);
      for (int i=t;i<nrows*64;i+=NT){
        int qm=i>>6,mm=(i>>5)&1,c=i&31;
        if (mm==0) KF[(rlo+qm)*33+c]=K0L[qm*33+c]; else VF[(rlo+qm)*33+c]=V0L[qm*33+c];
      }
      for (int i=t;i<onr*64;i+=NT){
        int qm=i>>6,mm=(i>>5)&1,c=i&31;
        float v=ld1( mm? &VB[(orlo+qm)*256+h*32+c] : &KB[(orlo+qm)*256+h*32+c]);
        if (mm==0) KF[(orlo+qm)*33+c]=v; else VF[(orlo+qm)*33+c]=v;
      }
      __syncthreads();
      for (int i2=0;i2<4;i2++){
        int ent=i2*NT+t; int qm=ent>>6, k=ent&63; int q=rlo+qm;
        float sc=-3.4e38f;
        if (q<tok && k<tok){
          sc=0.f;
#pragma unroll
          for (int j=0;j<32;j++) sc+=Q0L[qm*33+j]*KF[k*33+j];
          sc*=ISQ;
        }
        SC[qm*65+k]=sc;
      }
      __syncthreads();
      {
        int qm=t>>4, kk=t&15;
        float v0=SC[qm*65+kk], v1=SC[qm*65+kk+16], v2=SC[qm*65+kk+32], v3=SC[qm*65+kk+48];
        float mx=fmaxf(fmaxf(v0,v1),fmaxf(v2,v3));
#pragma unroll
        for (int m=8;m;m>>=1) mx=fmaxf(mx,__shfl_xor(mx,m,64));
        float e0=expf(v0-mx),e1=expf(v1-mx),e2=expf(v2-mx),e3=expf(v3-mx);
        float sd=e0+e1+e2+e3;
#pragma unroll
        for (int m=8;m;m>>=1) sd+=__shfl_xor(sd,m,64);
        float inv=1.f/sd;
        SC[qm*65+kk]=e0*inv; SC[qm*65+kk+16]=e1*inv;
        SC[qm*65+kk+32]=e2*inv; SC[qm*65+kk+48]=e3*inv;
      }
      __syncthreads();
      for (int i2=0;i2<2;i2++){
        int ent=i2*NT+t; int qm=ent>>5, c=ent&31; int q=rlo+qm;
        if (q<tok){
          float o=0.f;
          for (int k=0;k<tok;k++) o+=SC[qm*65+k]*VF[k*33+c];
          OL[qm*33+c]=o;
        }
      }
      __syncthreads();
      for (int i=t;i<nrows*32;i+=NT){
        int qm=i>>5,c=i&31;
        st1(&OV[(rlo+qm)*256+h*32+c], OL[qm*33+c]);
      }
    }
    cbar(&F[1], 32*tok);

    // ======== C3: per-(half,h) 4 rows: O-proj + LN -> K2/V2, q2/R2N ========
    if (wg<16){
      const int r0 = rlo + h*4;
      int nr=tok-r0; nr=nr<0?0:(nr>4?4:nr);
      const int qm0=h*4;
      if (nr>0){
        float* OVr=S; float* Z2r=S+1032;
        for (int i=t;i<nr*256;i+=NT){ int j=i>>8,c=i&255; OVr[j*258+c]=ld1(&OV[(r0+j)*256+c]); }
        __syncthreads();
        for (int i2=0;i2<2;i2++){
          int ent=i2*NT+t; int j=ent>>8, c=ent&255;
          if (j<nr){
            float acc=bo[c]+R1H[(qm0+j)*258+c];
            for (int jj=0;jj<256;jj++) acc+=OVr[j*258+jj]*Wo[jj*256+c];
            Z2r[j*258+c]=acc;
          }
        }
        __syncthreads();
        {
          int j=t>>7, s=t&127;
          float a=0.f,b=0.f,x0=0.f,x1=0.f;
          if (j<nr){
            x0=Z2r[j*258+s*2]; x1=Z2r[j*258+s*2+1];
            a=x0+x1; b=x0*x0+x1*x1;
          }
          float zs=wredsum(a), zq=wredsum(b);
          int w=t>>6;
          if ((t&63)==0){ redc[w*2]=zs; redc[w*2+1]=zq; }
          __syncthreads();
          if (j<nr){
            float ts=redc[4*j]+redc[4*j+2], tq=redc[4*j+1]+redc[4*j+3];
            float mu=ts*(1.f/256.f), var=tq*(1.f/256.f)-mu*mu;
            float rstd=1.f/sqrtf(var+1e-5f);
            float y0=(x0-mu)*rstd*lng[s*2]+lnb[s*2];
            float y1=(x1-mu)*rstd*lng[s*2+1]+lnb[s*2+1];
            Z2r[j*258+s*2]=y0; Z2r[j*258+s*2+1]=y1;
            if (r0+j==n){ st1(&R2N[s*2],y0); st1(&R2N[s*2+1],y1); }
          }
        }
        __syncthreads();
        for (int i2=0;i2<4;i2++){
          int ent=i2*NT+t; int m=ent>>10, j=(ent>>8)&3, c=ent&255;
          if (j<nr){
            const float* W = m? (Wv+65536):(Wk+65536);
            float acc = m? bv[256+c]:bk[256+c];
            for (int e=0;e<256;e++) acc+=Z2r[j*258+e]*W[e*256+c];
            st1( m? &V2G[(r0+j)*256+c] : &K2G[(r0+j)*256+c], acc);
          }
        }
        if (n>=r0 && n<r0+nr){
          int jn=n-r0;
          if (t<256){
            float acc=bq[256+t];
            for (int e=0;e<256;e++) acc+=Z2r[jn*258+e]*Wq[65536+e*256+t];
            st1(&Q2G[t],acc);
          }
        }
      }
    }
    cbar(&F[2], 32*tok);

    // ======== E2: attn1 row n, per head -> O3G ========
    if (wg<8){
      float* K2L=S; float* V2L=S+2112; float* q2L=S+4224; float* arowL=S+4260;
      const int h2=wg;
      for (int i=t;i<tok*64;i+=NT){
        int k=i>>6,mm=(i>>5)&1,c=i&31;
        float v=ld1( mm? &V2G[k*256+h2*32+c] : &K2G[k*256+h2*32+c]);
        if (mm==0) K2L[k*33+c]=v; else V2L[k*33+c]=v;
      }
      if (t<32) q2L[t]=ld1(&Q2G[h2*32+t]);
      __syncthreads();
      if (t<64){
        float sc=-3.4e38f;
        if (t<tok){
          sc=0.f;
#pragma unroll
          for (int j=0;j<32;j++) sc+=q2L[j]*K2L[t*33+j];
          sc*=ISQ;
        }
        float mx=wredmax(sc);
        float ex=(t<tok)? expf(sc-mx):0.f;
        float sd=wredsum(ex);
        arowL[t]=ex/sd;
      }
      __syncthreads();
      if (t<32){
        float o=0.f;
        for (int k=0;k<tok;k++) o+=arowL[k]*V2L[k*33+t];
        st1(&O3G[h2*32+t],o);
      }
    }
    cbar(&F[3], 32*tok);

    // ======== H: z3 + LN + logits (500 cols/WG) + argmax + winner ========
    {
      float* o3F=S; float* R2NL=S+256; float* zpart=S+512; float* outnL=S+1024;
      if (t<256){ o3F[t]=ld1(&O3G[t]); R2NL[t]=ld1(&R2N[t]); }
      __syncthreads();
      {
        int c=t&255,p=t>>8;
        float acc=0.f;
        for (int j=p*128;j<p*128+128;j++) acc+=o3F[j]*Wo[65536+j*256+c];
        zpart[p*256+c]=acc;
      }
      __syncthreads();
      if (t<256){
        float z=bo[256+t]+R2NL[t]+zpart[t]+zpart[256+t];
        float zs=wredsum(z), zq=wredsum(z*z);
        int w=t>>6;
        if ((t&63)==0){ sredv[w]=zs; sredv[8+w]=zq; }
        outnL[t]=z;
      }
      __syncthreads();
      if (t<256){
        float ts=sredv[0]+sredv[1]+sredv[2]+sredv[3];
        float tq=sredv[8]+sredv[9]+sredv[10]+sredv[11];
        float mu=ts*(1.f/256.f), var=tq*(1.f/256.f)-mu*mu;
        float rstd=1.f/sqrtf(var+1e-5f);
        outnL[t]=(outnL[t]-mu)*rstd*lng[256+t]+lnb[256+t];
      }
      __syncthreads();
      u64 key=0ull;
      if (t<500){
        int col=wg*500+t;
        float acc=sb[col];
        for (int e=0;e<256;e++) acc+=outnL[e]*sw[e*16000+col];
        unsigned int fb=__float_as_uint(acc);
        fb=(fb&0x80000000u)? ~fb : (fb|0x80000000u);
        key=(((u64)fb)<<32)|(u64)(~(unsigned int)col);
      }
#pragma unroll
      for (int m=32;m;m>>=1){ u64 o=shflx64(key,m); key=(o>key)?o:key; }
      if ((t&63)==0) sredU[t>>6]=key;
      __syncthreads();
      if (t==0){
        u64 kk=sredU[0];
#pragma unroll
        for (int w=1;w<8;w++) if (sredU[w]>kk) kk=sredU[w];
        __hip_atomic_fetch_max(&SLOT64[tok], kk, AS, AG);
      }
      __syncthreads();
      if (t==0){
        __hip_atomic_fetch_add(&F[4],1,AS,AG);
        if (wg==0){
          while (__hip_atomic_load(&F[4],AS,AG) < 32*tok) __builtin_amdgcn_s_sleep(2);
          u64 sf=__hip_atomic_load(&SLOT64[tok],AS,AG);
          int v=(int)(~(unsigned int)(sf&0xffffffffull));
          out[tok]=v;
          __hip_atomic_store(&WIN[tok], v+1, AS, AG);
        }
      }
      __syncthreads();
    }
  }
}

extern "C" void kernel_launch(void* const* d_in, const int* in_sizes, int n_in,
                              void* d_out, int out_size, void* d_ws, size_t ws_size,
                              hipStream_t stream)
{
  (void)in_sizes; (void)n_in; (void)out_size; (void)ws_size;
  hipLaunchKernelGGL(gen18124_kernel, dim3(NWG), dim3(NT), 108416, stream,
    (const float*)d_in[0],  (const float*)d_in[1],  (const float*)d_in[2],
    (const float*)d_in[3],  (const float*)d_in[4],  (const float*)d_in[5],
    (const float*)d_in[6],  (const float*)d_in[7],  (const float*)d_in[8],
    (const float*)d_in[9],  (const float*)d_in[10], (const float*)d_in[11],
    (const float*)d_in[12], (const float*)d_in[13], (const float*)d_in[14],
    (const float*)d_in[15], (int*)d_out, (float*)d_ws);
}

// Round 8
// 29120.499 us; speedup vs baseline: 1.3608x; 1.0104x over previous
//
#include <hip/hip_runtime.h>
#include <stdint.h>

// Persistent-kernel autoregressive decode for Generator_18124761989654.
// R8 = R6's proven-correct dataflow (recompute R1/QKV0/attn0/z2/K2V2 for ALL
// rows each step -- the growing kmask makes old rows change every step;
// R7's append-only assumption was the correctness bug) + R7's sync hygiene:
//  - F0..F4 counters and EP0..EP4 epoch lines each on own 256B line
//    (R6 regression: all counters + sleepless WIN spin shared ONE line).
//  - hybrid barriers: 32 arrivals -> counter; WG0 polls counter, publishes
//    written-once epoch line; 31 WGs poll the read-only epoch. All polls sleep.
//  - WIN[] stride-16 ints, sleepy poll.

#define NWG 32
#define NT 512
#define AS __ATOMIC_RELAXED
#define AG __HIP_MEMORY_SCOPE_AGENT

typedef unsigned long long u64;

__device__ __forceinline__ float ld1(const float* p){ return __hip_atomic_load(p,AS,AG); }
__device__ __forceinline__ void st1(float* p,float v){ __hip_atomic_store(p,v,AS,AG); }
__device__ __forceinline__ int  ldi(const int* p){ return __hip_atomic_load(p,AS,AG); }
__device__ __forceinline__ void sti(int* p,int v){ __hip_atomic_store(p,v,AS,AG); }

__device__ __forceinline__ float wredsum(float v){
#pragma unroll
  for (int m=32;m;m>>=1) v += __shfl_xor(v,m,64);
  return v;
}
__device__ __forceinline__ float wredmax(float v){
#pragma unroll
  for (int m=32;m;m>>=1) v = fmaxf(v,__shfl_xor(v,m,64));
  return v;
}
__device__ __forceinline__ u64 shflx64(u64 v,int m){
  unsigned int lo=(unsigned int)(v&0xffffffffull), hi=(unsigned int)(v>>32);
  lo=__shfl_xor(lo,m,64); hi=__shfl_xor(hi,m,64);
  return (((u64)hi)<<32)|(u64)lo;
}
__device__ __forceinline__ float pe_val(int l, int e){
  int j = e >> 1;
  float dv = expf((float)(2*j) * (-0.035977892078031970f));
  float arg = (float)l * dv;
  return (e & 1) ? cosf(arg) : sinf(arg);
}

// fenced device barrier (prelude only; epoch-equality => poison-safe)
__device__ __forceinline__ void gbar_f(int* arr, int* rel, int ep){
  __syncthreads();
  if (threadIdx.x==0){
    __builtin_amdgcn_fence(__ATOMIC_RELEASE, "agent");
    __hip_atomic_store(arr + blockIdx.x*16, ep, AS, AG);
  }
  if (blockIdx.x==0){
    if (threadIdx.x < NWG){
      while (__hip_atomic_load(arr + threadIdx.x*16, AS, AG) != ep)
        __builtin_amdgcn_s_sleep(1);
    }
    __syncthreads();
    if (threadIdx.x==0)
      __hip_atomic_store(rel, ep, AS, AG);
  }
  if (threadIdx.x==0){
    while (__hip_atomic_load(rel, AS, AG) != ep)
      __builtin_amdgcn_s_sleep(1);
    __builtin_amdgcn_fence(__ATOMIC_ACQUIRE, "agent");
  }
  __syncthreads();
}

// hybrid counter+epoch barrier: adders hit cnt; WG0 polls cnt, publishes ep;
// others poll the written-once epoch line. Monotonic => poison-safe.
__device__ __forceinline__ void cbar(int* cnt, int* epl, int tgt, int tokv, int wg){
  __syncthreads();
  if (threadIdx.x==0){
    __hip_atomic_fetch_add(cnt,1,AS,AG);
    if (wg==0){
      while (ldi(cnt) < tgt) __builtin_amdgcn_s_sleep(4);
      sti(epl, tokv);
    } else {
      while (ldi(epl) < tokv) __builtin_amdgcn_s_sleep(4);
    }
  }
  __syncthreads();
}

extern "C" __global__ __launch_bounds__(512, 1)
void gen18124_kernel(const float* __restrict__ noise,
                     const float* __restrict__ iw, const float* __restrict__ ib,
                     const float* __restrict__ Wq, const float* __restrict__ bq,
                     const float* __restrict__ Wk, const float* __restrict__ bk,
                     const float* __restrict__ Wv, const float* __restrict__ bv,
                     const float* __restrict__ Wo, const float* __restrict__ bo,
                     const float* __restrict__ lng, const float* __restrict__ lnb,
                     const float* __restrict__ emb, const float* __restrict__ sw,
                     const float* __restrict__ sb,
                     int* __restrict__ out, float* __restrict__ ws)
{
  const float ISQ = 0.17677669529663687f; // 1/sqrt(32)
  __shared__ int s_win;
  __shared__ float sredv[16];
  __shared__ float redc[16];
  __shared__ u64 sredU[8];
  extern __shared__ float pool[];

  // ---- LDS pool layout (floats) ----
  float* YH  = pool;          // [32][258] own-half Y cache (persistent)
  float* R1H = pool+8256;     // [32][258] own-half R1 (per step)
  float* K0L = pool+16512;    // [32][33]
  float* V0L = pool+17568;    // [32][33]
  float* Q0L = pool+18624;    // [32][33]
  float* S   = pool+19680;    // 7424-float phase scratch (aliased)

  // ---- workspace (float offsets) ----
  float* WVEC = ws;            // 64
  float* SKC  = ws+64;         // [2][256]
  float* SVC  = ws+576;        // [2][256]
  float* KAP  = ws+1088;       // [2][8][256]
  float* UT   = ws+5184;       // [2][8][256]
  float* CC   = ws+9280;       // [2][256]
  float* BETA = ws+9792;       // [2][8]
  int* ARR = (int*)(ws+9824);  // 32*16 gbar_f flags
  int* REL = (int*)(ws+10336);
  int* F0   = (int*)(ws+10400);   // each on own 256B line
  int* F1   = (int*)(ws+10464);
  int* F2   = (int*)(ws+10528);
  int* F3   = (int*)(ws+10592);
  int* F4   = (int*)(ws+10656);
  int* EP0  = (int*)(ws+10720);
  int* EP1  = (int*)(ws+10784);
  int* EP2  = (int*)(ws+10848);
  int* EP3  = (int*)(ws+10912);
  int* EP4  = (int*)(ws+10976);
  int* WIN  = (int*)(ws+11040);   // [64] stride-16 ints (winner+1)
  u64* SLOT64=(u64*)(ws+12064);   // [64]
  float* KB  = ws+12192;       // [64][256]
  float* VB  = ws+28576;       // [64][256]
  float* OV  = ws+44960;       // [64][256] attn0 outputs (head-concat)
  float* K2G = ws+61344;       // [64][256]
  float* V2G = ws+77728;       // [64][256]
  float* Q2G = ws+94112;       // [256]
  float* R2N = ws+94368;       // [256]
  float* O3G = ws+94624;       // [256]

  const int wg = blockIdx.x, t = threadIdx.x;
  int ep = 0;

  // ================= Prelude 0: zero ctrl, colsums, WVEC =================
  {
    if (wg==1){
      if (t<64) __hip_atomic_store(&SLOT64[t], 0ull, AS, AG);
      else if (t==64) sti(F0,0);
      else if (t==65) sti(F1,0);
      else if (t==66) sti(F2,0);
      else if (t==67) sti(F3,0);
      else if (t==68) sti(F4,0);
      else if (t==70) sti(EP0,0);
      else if (t==71) sti(EP1,0);
      else if (t==72) sti(EP2,0);
      else if (t==73) sti(EP3,0);
      else if (t==74) sti(EP4,0);
      else if (t>=128 && t<192) sti(&WIN[(t-128)*16], (t==128)?1:0);
      else if (t==200) out[0]=0;
    }
    // colsums of Wk/Wv both layers: col = wg*8 + wave
    for (int it=0; it<4; it++){
      const float* M = (it>=2)? Wv : Wk;
      int base=(it&1)*65536;
      int col=wg*8+(t>>6);
      int r0=(t&63)*4;
      float a=0.f;
#pragma unroll
      for (int i=0;i<4;i++) a+=M[base+(r0+i)*256+col];
      a=wredsum(a);
      if ((t&63)==0){
        if (it<2) SKC[(it&1)*256+col]=a; else SVC[(it&1)*256+col]=a;
      }
    }
    if (wg==0){
      float* wl=S;
      if (t<64) wl[t]=noise[t];
      __syncthreads();
      for (int i=0;i<4;i++){
        float acc=0.f;
        if (t<64){
          for (int in_=0;in_<64;in_++) acc += wl[in_]*iw[(i*64+in_)*64+t];
          acc += ib[i*64+t];
        }
        __syncthreads();
        if (t<64) wl[t]=acc;
        __syncthreads();
      }
      if (t<64) WVEC[t]=wl[t];
    }
  }
  gbar_f(ARR,REL,++ep);

  // ================= Prelude 1: tables =================
  {
    int c0=wg*8;
    { // CC: 16 ents x 32-thread partial
      int ent=t>>5, rr=t&31;
      int i=ent>>3, c=c0+(ent&7);
      float p=0.f;
      for (int r=rr*8;r<rr*8+8;r++) p += bv[i*256+r]*Wo[i*65536+r*256+c];
#pragma unroll
      for (int m=16;m;m>>=1) p+=__shfl_xor(p,m,64);
      if ((t&31)==0) CC[i*256+c]=p+bo[i*256+c];
    }
    if (t<128){ // UT
      int i=t>>6, h=(t>>3)&7, c=c0+(t&7);
      float s=0.f;
      for (int e2=0;e2<32;e2++) s += SVC[i*256+h*32+e2]*Wo[i*65536+(h*32+e2)*256+c];
      UT[(i*8+h)*256+c]=s;
    } else if (t<256){ // KAP
      int ent=wg*128+(t-128);
      int i=ent>>11, h=(ent>>8)&7, e=ent&255;
      float s=0.f;
      for (int c2=0;c2<32;c2++) s += Wq[i*65536+e*256+h*32+c2]*SKC[i*256+h*32+c2];
      KAP[(i*8+h)*256+e]=s;
    } else if (wg==0 && t<272){ // BETA
      int u=t-256, i=u>>3, h=u&7;
      float s=0.f;
      for (int c2=0;c2<32;c2++) s += bq[i*256+h*32+c2]*SKC[i*256+h*32+c2];
      BETA[i*8+h]=s;
    }
  }
  gbar_f(ARR,REL,++ep);

  const int h = wg&7, half = (wg>>3)&1;
  const int rlo = half*32;

  // ================= decode loop =================
  for (int tok=1; tok<64; tok++){
    const int n = tok-1;
    int nrows = tok-rlo; nrows = nrows<0?0:(nrows>32?32:nrows);

    // ======== C1: Y append + R1 (local) + K0/V0/Q0 head h ========
    if (wg<16){
      if (n>=rlo && n<rlo+32){
        if (t==0){
          int w;
          while ((w=ldi(&WIN[n*16]))==0) __builtin_amdgcn_s_sleep(4);
          s_win=w-1;
        }
        __syncthreads();
        int v=s_win;
        for (int c=t;c<256;c+=NT) YH[(n-rlo)*258+c]=emb[v*256+c]+pe_val(n,c);
      }
      __syncthreads();
      if (nrows>0){
        float* m8L=S; // [32][8]
        for (int i=t;i<nrows*256;i+=NT){ int qm=i>>8,c=i&255; R1H[qm*258+c]=YH[qm*258+c]; }
        __syncthreads();
        for (int blk=0;blk<2;blk++){
          if (t<nrows*8){
            int qm=t>>3, h2=t&7;
            const float* kap=&KAP[(blk*8+h2)*256];
            float dot=0.f;
            for (int e=0;e<256;e++) dot += R1H[qm*258+e]*kap[e];
            float alpha=(dot+BETA[blk*8+h2])*ISQ;
            float mx=-3.4e38f;
            for (int k=0;k<tok;k++) mx=fmaxf(mx,alpha*WVEC[k]);
            float sn=0.f,sd=0.f;
            for (int k=0;k<tok;k++){ float e_=expf(alpha*WVEC[k]-mx); sn+=e_*WVEC[k]; sd+=e_; }
            m8L[qm*8+h2]=sn/sd;
          }
          __syncthreads();
          {
            int qm=t>>4, s=t&15;
            if (qm<nrows){
              float zv[16]; float zs=0.f,zq=0.f;
              for (int i=0;i<16;i++){
                int e=s*16+i;
                float z=CC[blk*256+e]+R1H[qm*258+e];
#pragma unroll
                for (int h2=0;h2<8;h2++) z+=m8L[qm*8+h2]*UT[(blk*8+h2)*256+e];
                zv[i]=z; zs+=z; zq+=z*z;
              }
#pragma unroll
              for (int m=8;m;m>>=1){ zs+=__shfl_xor(zs,m,64); zq+=__shfl_xor(zq,m,64); }
              float mu=zs*(1.f/256.f), var=zq*(1.f/256.f)-mu*mu;
              float rstd=1.f/sqrtf(var+1e-5f);
              for (int i=0;i<16;i++){
                int e=s*16+i;
                R1H[qm*258+e]=(zv[i]-mu)*rstd*lng[blk*256+e]+lnb[blk*256+e];
              }
            }
          }
          __syncthreads();
        }
        // K0/V0/Q0 (head h, own-half rows)
        for (int i2=0;i2<6;i2++){
          int ent=i2*NT+t;
          int m=ent>>10, qm=(ent>>5)&31, c=ent&31;
          if (qm<nrows){
            int col=h*32+c;
            const float* W=(m==0)?Wk:((m==1)?Wv:Wq);
            float acc=(m==0)?bk[col]:((m==1)?bv[col]:bq[col]);
            for (int e=0;e<256;e++) acc += R1H[qm*258+e]*W[e*256+col];
            if (m==0){ K0L[qm*33+c]=acc; st1(&KB[(rlo+qm)*256+col],acc); }
            else if (m==1){ V0L[qm*33+c]=acc; st1(&VB[(rlo+qm)*256+col],acc); }
            else Q0L[qm*33+c]=acc;
          }
        }
      }
    }
    cbar(F0,EP0,32*tok,tok,wg);

    // ======== C2: attn0 (head h, own-half rows) -> OV ========
    if (wg<16 && nrows>0){
      float* KF=S; float* VF=S+2112; float* SC=S+4224; float* OL=S+6304;
      const int orlo=(1-half)*32;
      int onr=tok-orlo; onr=onr<0?0:(onr>32?32:onr);
      for (int i=t;i<nrows*64;i+=NT){
        int qm=i>>6,mm=(i>>5)&1,c=i&31;
        if (mm==0) KF[(rlo+qm)*33+c]=K0L[qm*33+c]; else VF[(rlo+qm)*33+c]=V0L[qm*33+c];
      }
      for (int i=t;i<onr*64;i+=NT){
        int qm=i>>6,mm=(i>>5)&1,c=i&31;
        float v=ld1( mm? &VB[(orlo+qm)*256+h*32+c] : &KB[(orlo+qm)*256+h*32+c]);
        if (mm==0) KF[(orlo+qm)*33+c]=v; else VF[(orlo+qm)*33+c]=v;
      }
      __syncthreads();
      for (int i2=0;i2<4;i2++){
        int ent=i2*NT+t; int qm=ent>>6, k=ent&63; int q=rlo+qm;
        float sc=-3.4e38f;
        if (q<tok && k<tok){
          sc=0.f;
#pragma unroll
          for (int j=0;j<32;j++) sc+=Q0L[qm*33+j]*KF[k*33+j];
          sc*=ISQ;
        }
        SC[qm*65+k]=sc;
      }
      __syncthreads();
      {
        int qm=t>>4, kk=t&15;
        float v0=SC[qm*65+kk], v1=SC[qm*65+kk+16], v2=SC[qm*65+kk+32], v3=SC[qm*65+kk+48];
        float mx=fmaxf(fmaxf(v0,v1),fmaxf(v2,v3));
#pragma unroll
        for (int m=8;m;m>>=1) mx=fmaxf(mx,__shfl_xor(mx,m,64));
        float e0=expf(v0-mx),e1=expf(v1-mx),e2=expf(v2-mx),e3=expf(v3-mx);
        float sd=e0+e1+e2+e3;
#pragma unroll
        for (int m=8;m;m>>=1) sd+=__shfl_xor(sd,m,64);
        float inv=1.f/sd;
        SC[qm*65+kk]=e0*inv; SC[qm*65+kk+16]=e1*inv;
        SC[qm*65+kk+32]=e2*inv; SC[qm*65+kk+48]=e3*inv;
      }
      __syncthreads();
      for (int i2=0;i2<2;i2++){
        int ent=i2*NT+t; int qm=ent>>5, c=ent&31; int q=rlo+qm;
        if (q<tok){
          float o=0.f;
          for (int k=0;k<tok;k++) o+=SC[qm*65+k]*VF[k*33+c];
          OL[qm*33+c]=o;
        }
      }
      __syncthreads();
      for (int i=t;i<nrows*32;i+=NT){
        int qm=i>>5,c=i&31;
        st1(&OV[(rlo+qm)*256+h*32+c], OL[qm*33+c]);
      }
    }
    cbar(F1,EP1,32*tok,tok,wg);

    // ======== C3: per-(half,h) 4 rows: O-proj + LN -> K2/V2, q2/R2N ========
    if (wg<16){
      const int r0 = rlo + h*4;
      int nr=tok-r0; nr=nr<0?0:(nr>4?4:nr);
      const int qm0=h*4;
      if (nr>0){
        float* OVr=S; float* Z2r=S+1032;
        for (int i=t;i<nr*256;i+=NT){ int j=i>>8,c=i&255; OVr[j*258+c]=ld1(&OV[(r0+j)*256+c]); }
        __syncthreads();
        for (int i2=0;i2<2;i2++){
          int ent=i2*NT+t; int j=ent>>8, c=ent&255;
          if (j<nr){
            float acc=bo[c]+R1H[(qm0+j)*258+c];
            for (int jj=0;jj<256;jj++) acc+=OVr[j*258+jj]*Wo[jj*256+c];
            Z2r[j*258+c]=acc;
          }
        }
        __syncthreads();
        {
          int j=t>>7, s=t&127;
          float a=0.f,b=0.f,x0=0.f,x1=0.f;
          if (j<nr){
            x0=Z2r[j*258+s*2]; x1=Z2r[j*258+s*2+1];
            a=x0+x1; b=x0*x0+x1*x1;
          }
          float zs=wredsum(a), zq=wredsum(b);
          int w=t>>6;
          if ((t&63)==0){ redc[w*2]=zs; redc[w*2+1]=zq; }
          __syncthreads();
          if (j<nr){
            float ts=redc[4*j]+redc[4*j+2], tq=redc[4*j+1]+redc[4*j+3];
            float mu=ts*(1.f/256.f), var=tq*(1.f/256.f)-mu*mu;
            float rstd=1.f/sqrtf(var+1e-5f);
            float y0=(x0-mu)*rstd*lng[s*2]+lnb[s*2];
            float y1=(x1-mu)*rstd*lng[s*2+1]+lnb[s*2+1];
            Z2r[j*258+s*2]=y0; Z2r[j*258+s*2+1]=y1;
            if (r0+j==n){ st1(&R2N[s*2],y0); st1(&R2N[s*2+1],y1); }
          }
        }
        __syncthreads();
        for (int i2=0;i2<4;i2++){
          int ent=i2*NT+t; int m=ent>>10, j=(ent>>8)&3, c=ent&255;
          if (j<nr){
            const float* W = m? (Wv+65536):(Wk+65536);
            float acc = m? bv[256+c]:bk[256+c];
            for (int e=0;e<256;e++) acc+=Z2r[j*258+e]*W[e*256+c];
            st1( m? &V2G[(r0+j)*256+c] : &K2G[(r0+j)*256+c], acc);
          }
        }
        if (n>=r0 && n<r0+nr){
          int jn=n-r0;
          if (t<256){
            float acc=bq[256+t];
            for (int e=0;e<256;e++) acc+=Z2r[jn*258+e]*Wq[65536+e*256+t];
            st1(&Q2G[t],acc);
          }
        }
      }
    }
    cbar(F2,EP2,32*tok,tok,wg);

    // ======== E2: attn1 row n, per head -> O3G ========
    if (wg<8){
      float* K2L=S; float* V2L=S+2112; float* q2L=S+4224; float* arowL=S+4260;
      const int h2=wg;
      for (int i=t;i<tok*64;i+=NT){
        int k=i>>6,mm=(i>>5)&1,c=i&31;
        float v=ld1( mm? &V2G[k*256+h2*32+c] : &K2G[k*256+h2*32+c]);
        if (mm==0) K2L[k*33+c]=v; else V2L[k*33+c]=v;
      }
      if (t<32) q2L[t]=ld1(&Q2G[h2*32+t]);
      __syncthreads();
      if (t<64){
        float sc=-3.4e38f;
        if (t<tok){
          sc=0.f;
#pragma unroll
          for (int j=0;j<32;j++) sc+=q2L[j]*K2L[t*33+j];
          sc*=ISQ;
        }
        float mx=wredmax(sc);
        float ex=(t<tok)? expf(sc-mx):0.f;
        float sd=wredsum(ex);
        arowL[t]=ex/sd;
      }
      __syncthreads();
      if (t<32){
        float o=0.f;
        for (int k=0;k<tok;k++) o+=arowL[k]*V2L[k*33+t];
        st1(&O3G[h2*32+t],o);
      }
    }
    cbar(F3,EP3,32*tok,tok,wg);

    // ======== H: z3 + LN + logits (500 cols/WG) + argmax + winner ========
    {
      float* o3F=S; float* R2NL=S+256; float* zpart=S+512; float* outnL=S+1024;
      if (t<256){ o3F[t]=ld1(&O3G[t]); R2NL[t]=ld1(&R2N[t]); }
      __syncthreads();
      {
        int c=t&255,p=t>>8;
        float acc=0.f;
        for (int j=p*128;j<p*128+128;j++) acc+=o3F[j]*Wo[65536+j*256+c];
        zpart[p*256+c]=acc;
      }
      __syncthreads();
      if (t<256){
        float z=bo[256+t]+R2NL[t]+zpart[t]+zpart[256+t];
        float zs=wredsum(z), zq=wredsum(z*z);
        int w=t>>6;
        if ((t&63)==0){ sredv[w]=zs; sredv[8+w]=zq; }
        outnL[t]=z;
      }
      __syncthreads();
      if (t<256){
        float ts=sredv[0]+sredv[1]+sredv[2]+sredv[3];
        float tq=sredv[8]+sredv[9]+sredv[10]+sredv[11];
        float mu=ts*(1.f/256.f), var=tq*(1.f/256.f)-mu*mu;
        float rstd=1.f/sqrtf(var+1e-5f);
        outnL[t]=(outnL[t]-mu)*rstd*lng[256+t]+lnb[256+t];
      }
      __syncthreads();
      u64 key=0ull;
      if (t<500){
        int col=wg*500+t;
        float acc=sb[col];
        for (int e=0;e<256;e++) acc+=outnL[e]*sw[e*16000+col];
        unsigned int fb=__float_as_uint(acc);
        fb=(fb&0x80000000u)? ~fb : (fb|0x80000000u);
        key=(((u64)fb)<<32)|(u64)(~(unsigned int)col);
      }
#pragma unroll
      for (int m=32;m;m>>=1){ u64 o=shflx64(key,m); key=(o>key)?o:key; }
      if ((t&63)==0) sredU[t>>6]=key;
      __syncthreads();
      if (t==0){
        u64 kk=sredU[0];
#pragma unroll
        for (int w=1;w<8;w++) if (sredU[w]>kk) kk=sredU[w];
        __hip_atomic_fetch_max(&SLOT64[tok], kk, AS, AG);
      }
      __syncthreads();   // drains t0's atomicMax before the counter add
      if (t==0){
        __hip_atomic_fetch_add(F4,1,AS,AG);
        if (wg==0){
          while (ldi(F4) < 32*tok) __builtin_amdgcn_s_sleep(4);
          u64 sf=__hip_atomic_load(&SLOT64[tok],AS,AG);
          int v=(int)(~(unsigned int)(sf&0xffffffffull));
          out[tok]=v;
          sti(&WIN[tok*16], v+1);
          sti(EP4, tok);
        } else {
          while (ldi(EP4) < tok) __builtin_amdgcn_s_sleep(4);
        }
      }
      __syncthreads();
    }
  }
}

extern "C" void kernel_launch(void* const* d_in, const int* in_sizes, int n_in,
                              void* d_out, int out_size, void* d_ws, size_t ws_size,
                              hipStream_t stream)
{
  (void)in_sizes; (void)n_in; (void)out_size; (void)ws_size;
  hipLaunchKernelGGL(gen18124_kernel, dim3(NWG), dim3(NT), 108416, stream,
    (const float*)d_in[0],  (const float*)d_in[1],  (const float*)d_in[2],
    (const float*)d_in[3],  (const float*)d_in[4],  (const float*)d_in[5],
    (const float*)d_in[6],  (const float*)d_in[7],  (const float*)d_in[8],
    (const float*)d_in[9],  (const float*)d_in[10], (const float*)d_in[11],
    (const float*)d_in[12], (const float*)d_in[13], (const float*)d_in[14],
    (const float*)d_in[15], (int*)d_out, (float*)d_ws);
}